// Round 4
// baseline (2024.654 us; speedup 1.0000x reference)
//
#include <hip/hip_runtime.h>
#include <cmath>

#define HS 32768
#define NL 16
#define WPL 16   // workgroup slices per level -> 16*16 = 256 WGs, 1/CU
#define TPB 1024

typedef float fvec4 __attribute__((ext_vector_type(4)));

struct ResArr { int r[16]; };

// ---------------- Kernel P: normalize coords ONCE (exact reference arithmetic).
// Output c[N][4] fp32 lives in the head of `out` (dead until kernel T overwrites).
__global__ __launch_bounds__(256) void hash4d_pre_kernel(
    const float* __restrict__ coords, const float* __restrict__ tstamps,
    float* __restrict__ cbuf, int npts)
{
    int p = blockIdx.x * 256 + threadIdx.x;
    if (p >= npts) return;
    float x = coords[3 * p + 0];
    float y = coords[3 * p + 1];
    float z = coords[3 * p + 2];
    float t = tstamps[p];
    t = fminf(fmaxf(t, 0.0f), 1.0f);
    // exact same ops as reference: add then true divide (bit-identical floors later)
    fvec4 c = { (x + 50.0f) / 100.0f,
                (y + 50.0f) / 100.0f,
                (z + 50.0f) / 100.0f,
                t };
    *(fvec4*)(cbuf + 4 * (size_t)p) = c;
}

// ---------------- Kernel A': one level per WG, table staged ONCE, free-running loop.
// ws[L][N] float2 stores are lane-contiguous (512 B/wave per instruction) -> amp 1.0.
__global__ __launch_bounds__(TPB, 1) void hash4d_level_kernel(
    const float* __restrict__ cbuf,
    const float* __restrict__ tables,
    float2* __restrict__ ws,
    int npts, ResArr res)
{
    __shared__ unsigned lds_tab[HS];   // 128 KB: two bf16 feats packed per entry

    const int level = blockIdx.x & 15;
    const int slice = blockIdx.x >> 4;
    const int tid   = (int)threadIdx.x;

    const unsigned P1 = 2654435761u, P2 = 805459861u, P3 = 3674653429u;
    const unsigned MASK4 = (HS - 1u) << 2;   // hash mask pre-shifted to byte offset

    {   // stage table: fvec4 loads (2 entries), pack bf16x2 (RNE), b64 writes
        const fvec4* gt = (const fvec4*)(tables + (size_t)level * HS * 2);
        #pragma unroll 4
        for (int j = tid; j < HS / 2; j += TPB) {
            fvec4 v = gt[j];
            unsigned u0 = __float_as_uint(v.x), u1 = __float_as_uint(v.y);
            unsigned u2 = __float_as_uint(v.z), u3 = __float_as_uint(v.w);
            unsigned r0 = u0 + 0x7fffu + ((u0 >> 16) & 1u);
            unsigned r1 = u1 + 0x7fffu + ((u1 >> 16) & 1u);
            unsigned r2 = u2 + 0x7fffu + ((u2 >> 16) & 1u);
            unsigned r3 = u3 + 0x7fffu + ((u3 >> 16) & 1u);
            uint2 pk;
            pk.x = __builtin_amdgcn_perm(r1, r0, 0x07060302u);
            pk.y = __builtin_amdgcn_perm(r3, r2, 0x07060302u);
            *(uint2*)&lds_tab[2 * j] = pk;
        }
    }
    __syncthreads();   // the ONLY barrier in this kernel

    const float rf = (float)res.r[level];
    float2* wsl = ws + (size_t)level * npts;

    const int per   = (npts + WPL - 1) / WPL;
    const int start = slice * per;
    const int end   = min(start + per, npts);

    for (int i = start + tid; i < end; i += TPB) {
        fvec4 c = *(const fvec4*)(cbuf + 4 * (size_t)i);   // 16 B coalesced

        float s0 = c.x * rf, s1 = c.y * rf, s2 = c.z * rf, s3 = c.w * rf;
        float g0 = floorf(s0), g1 = floorf(s1), g2 = floorf(s2), g3 = floorf(s3);
        float f0 = s0 - g0, f1 = s1 - g1, f2 = s2 - g2, f3 = s3 - g3;

        // primes pre-shifted <<2: (x*P)<<2 == x*(P<<2) mod 2^32
        unsigned a0 = ((unsigned)(int)g0) << 2;
        unsigned a1 = (unsigned)(int)g1 * (P1 << 2);
        unsigned a2 = (unsigned)(int)g2 * (P2 << 2);
        unsigned a3 = (unsigned)(int)g3 * (P3 << 2);
        unsigned b0 = a0 + 4u;
        unsigned b1 = a1 + (P1 << 2);
        unsigned b2 = a2 + (P2 << 2);
        unsigned b3 = a3 + (P3 << 2);

        // precombine low-pair XORs: 1 xor per gather instead of 2
        unsigned lo01[4] = { a0 ^ a1, b0 ^ a1, a0 ^ b1, b0 ^ b1 };

        float m0 = 1.0f - f0, m1 = 1.0f - f1, m2 = 1.0f - f2, m3 = 1.0f - f3;
        float w01_0 = m0 * m1, w01_1 = f0 * m1, w01_2 = m0 * f1, w01_3 = f0 * f1;
        float w23_0 = m2 * m3, w23_1 = f2 * m3, w23_2 = m2 * f3, w23_3 = f2 * f3;

        float A = 0.0f, B = 0.0f;
        #pragma unroll
        for (int hi = 0; hi < 4; ++hi) {
            unsigned hb = ((hi & 1) ? b2 : a2) ^ ((hi & 2) ? b3 : a3);
            float whi = (hi == 0) ? w23_0 : (hi == 1) ? w23_1 : (hi == 2) ? w23_2 : w23_3;
            float ax = 0.0f, ay = 0.0f;
            #pragma unroll
            for (int lo = 0; lo < 4; ++lo) {
                unsigned off = (hb ^ lo01[lo]) & MASK4;
                float wlo = (lo == 0) ? w01_0 : (lo == 1) ? w01_1 : (lo == 2) ? w01_2 : w01_3;
                unsigned pk = *(const unsigned*)((const char*)lds_tab + off);
                ax = fmaf(wlo, __uint_as_float(pk << 16), ax);
                ay = fmaf(wlo, __uint_as_float(pk & 0xffff0000u), ay);
            }
            A = fmaf(whi, ax, A);
            B = fmaf(whi, ay, B);
        }
        wsl[i] = make_float2(A, B);   // lane-contiguous f2: full sectors per instr
    }
}

// ---------------- Kernel T: ws[16][N]f2 -> out[N][32], full lines both directions.
__global__ __launch_bounds__(256, 4) void hash4d_out_kernel(
    const float* __restrict__ ws, float* __restrict__ out, int npts)
{
    __shared__ float2 lt[256][17];   // +1 pad: b64 accesses at the 4-way bank minimum
    const int tid  = (int)threadIdx.x;
    const int base = (int)blockIdx.x * 256;

    if (base + 256 <= npts) {
        #pragma unroll
        for (int L = 0; L < NL; ++L) {
            // 64 lanes x 8 B contiguous = 512 B per instruction
            lt[tid][L] = ((const float2*)ws)[(size_t)L * npts + base + tid];
        }
        __syncthreads();
        const size_t ob = (size_t)base * 32;
        #pragma unroll
        for (int i = 0; i < 8; ++i) {
            int v  = i * 256 + tid;     // fvec4 index within the 256x32 tile
            int p  = v >> 3;            // local point
            int c4 = v & 7;             // 16 B chunk = level pair
            float2 e0 = lt[p][2 * c4 + 0];
            float2 e1 = lt[p][2 * c4 + 1];
            fvec4 o = { e0.x, e0.y, e1.x, e1.y };
            ((fvec4*)(out + ob))[v] = o;   // 1 KB/wave contiguous, full lines
        }
    } else {
        int p = base + tid;
        if (p < npts) {
            float* op = out + (size_t)p * 32;
            #pragma unroll
            for (int L = 0; L < NL; ++L) {
                float2 v = ((const float2*)ws)[(size_t)L * npts + p];
                op[2 * L + 0] = v.x;
                op[2 * L + 1] = v.y;
            }
        }
    }
}

// ---------------- Fallback (ws too small): direct global-gather kernel
__global__ __launch_bounds__(256, 4) void hash4d_kernel(
    const float* __restrict__ coords,
    const float* __restrict__ tstamps,
    const float* __restrict__ tables,
    float* __restrict__ out,
    int npts, ResArr res)
{
    int n = blockIdx.x * blockDim.x + threadIdx.x;
    if (n >= npts) return;

    float x = coords[3 * n + 0];
    float y = coords[3 * n + 1];
    float z = coords[3 * n + 2];
    float t = tstamps[n];
    t = fminf(fmaxf(t, 0.0f), 1.0f);

    float c0 = (x + 50.0f) / 100.0f;
    float c1 = (y + 50.0f) / 100.0f;
    float c2 = (z + 50.0f) / 100.0f;
    float c3 = t;

    const unsigned P1 = 2654435761u, P2 = 805459861u, P3 = 3674653429u;
    float acc[32];

    #pragma unroll
    for (int L = 0; L < NL; ++L) {
        float rf = (float)res.r[L];
        float s0 = c0 * rf, s1 = c1 * rf, s2 = c2 * rf, s3 = c3 * rf;
        float g0 = floorf(s0), g1 = floorf(s1), g2 = floorf(s2), g3 = floorf(s3);
        float f0 = s0 - g0, f1 = s1 - g1, f2 = s2 - g2, f3 = s3 - g3;

        unsigned a0 = (unsigned)(int)g0;
        unsigned a1 = (unsigned)(int)g1 * P1;
        unsigned a2 = (unsigned)(int)g2 * P2;
        unsigned a3 = (unsigned)(int)g3 * P3;
        unsigned b0 = a0 + 1u, b1 = a1 + P1, b2 = a2 + P2, b3 = a3 + P3;

        float w0a = 1.0f - f0, w0b = f0;
        float w1a = 1.0f - f1, w1b = f1;
        float w2a = 1.0f - f2, w2b = f2;
        float w3a = 1.0f - f3, w3b = f3;

        const float2* tab = ((const float2*)tables) + (size_t)L * (size_t)HS;
        float A = 0.0f, B = 0.0f;
        #pragma unroll
        for (int ci = 0; ci < 16; ++ci) {
            unsigned h = ((ci & 1) ? b0 : a0) ^ ((ci & 2) ? b1 : a1) ^
                         ((ci & 4) ? b2 : a2) ^ ((ci & 8) ? b3 : a3);
            float2 fv = tab[h & (HS - 1)];
            float w = ((((ci & 1) ? w0b : w0a) * ((ci & 2) ? w1b : w1a)) *
                       ((ci & 4) ? w2b : w2a)) * ((ci & 8) ? w3b : w3a);
            A += w * fv.x;
            B += w * fv.y;
        }
        acc[2 * L + 0] = A;
        acc[2 * L + 1] = B;
    }

    float* op = out + (size_t)n * 32;
    #pragma unroll
    for (int i = 0; i < 8; ++i) {
        fvec4 v = { acc[4 * i + 0], acc[4 * i + 1],
                    acc[4 * i + 2], acc[4 * i + 3] };
        *(fvec4*)(op + 4 * i) = v;
    }
}

extern "C" void kernel_launch(void* const* d_in, const int* in_sizes, int n_in,
                              void* d_out, int out_size, void* d_ws, size_t ws_size,
                              hipStream_t stream) {
    const float* coords  = (const float*)d_in[0];
    const float* tstamps = (const float*)d_in[1];
    const float* tables  = (const float*)d_in[2];
    float* out = (float*)d_out;

    // resolutions computed host-side with the same double-precision exp/log as the
    // reference (keeps int() truncation bit-identical; do NOT hardcode)
    ResArr ra;
    for (int l = 0; l < 16; ++l) {
        double f = (double)l / 15.0;
        double v = exp(log(16.0) * (1.0 - f) + log(512.0) * f);
        ra.r[l] = (int)v;
    }

    int n = in_sizes[0] / 3;
    size_t need = (size_t)n * 16 * sizeof(float2);

    if (ws_size >= need && out_size >= (int)((size_t)n * 32 * sizeof(float))) {
        // c[N][4] scratch lives in the head of `out` (16 B/point = 1/8 of out).
        // Safe: stream-ordered P -> A' -> T; T fully overwrites out afterwards.
        float* cbuf = out;
        hash4d_pre_kernel<<<(n + 255) / 256, 256, 0, stream>>>(
            coords, tstamps, cbuf, n);
        hash4d_level_kernel<<<16 * WPL, TPB, 0, stream>>>(
            cbuf, tables, (float2*)d_ws, n, ra);
        hash4d_out_kernel<<<(n + 255) / 256, 256, 0, stream>>>(
            (const float*)d_ws, out, n);
    } else {
        hash4d_kernel<<<(n + 255) / 256, 256, 0, stream>>>(
            coords, tstamps, tables, out, n, ra);
    }
}

// Round 5
// 485.367 us; speedup vs baseline: 4.1714x; 4.1714x over previous
//
#include <hip/hip_runtime.h>
#include <cmath>

#define HS 32768
#define NL 16
#define WPL 16   // workgroup slices per level -> 16*16 = 256 WGs, 1/CU
#define TPB 1024

typedef float fvec4 __attribute__((ext_vector_type(4)));

struct ResArr { int r[16]; };

// ---------------- Kernel P: normalize coords ONCE (exact reference arithmetic).
// Output c[N][4] fp32 lives in the head of `out` (dead until kernel T overwrites).
__global__ __launch_bounds__(256) void hash4d_pre_kernel(
    const float* __restrict__ coords, const float* __restrict__ tstamps,
    float* __restrict__ cbuf, int npts)
{
    int p = blockIdx.x * 256 + threadIdx.x;
    if (p >= npts) return;
    float x = coords[3 * p + 0];
    float y = coords[3 * p + 1];
    float z = coords[3 * p + 2];
    float t = tstamps[p];
    t = fminf(fmaxf(t, 0.0f), 1.0f);
    // exact same ops as reference: add then true divide (bit-identical floors later)
    fvec4 c = { (x + 50.0f) / 100.0f,
                (y + 50.0f) / 100.0f,
                (z + 50.0f) / 100.0f,
                t };
    *(fvec4*)(cbuf + 4 * (size_t)p) = c;
}

// ---------------- Kernel A': one level per WG, table staged ONCE, free-running loop.
// ws[L][N] float2 stores are lane-contiguous (512 B/wave per instruction) -> amp 1.0
// (measured round 0: WRITE 251 MB for 256 MB of ws).
__global__ __launch_bounds__(TPB, 1) void hash4d_level_kernel(
    const float* __restrict__ cbuf,
    const float* __restrict__ tables,
    float2* __restrict__ ws,
    int npts, ResArr res)
{
    __shared__ unsigned lds_tab[HS];   // 128 KB: two bf16 feats packed per entry

    const int level = blockIdx.x & 15;
    const int slice = blockIdx.x >> 4;
    const int tid   = (int)threadIdx.x;

    const unsigned P1 = 2654435761u, P2 = 805459861u, P3 = 3674653429u;
    const unsigned MASK4 = (HS - 1u) << 2;   // hash mask pre-shifted to byte offset

    {   // stage table: fvec4 loads (2 entries), pack bf16x2 (RNE), b64 writes
        const fvec4* gt = (const fvec4*)(tables + (size_t)level * HS * 2);
        #pragma unroll 4
        for (int j = tid; j < HS / 2; j += TPB) {
            fvec4 v = gt[j];
            unsigned u0 = __float_as_uint(v.x), u1 = __float_as_uint(v.y);
            unsigned u2 = __float_as_uint(v.z), u3 = __float_as_uint(v.w);
            unsigned r0 = u0 + 0x7fffu + ((u0 >> 16) & 1u);
            unsigned r1 = u1 + 0x7fffu + ((u1 >> 16) & 1u);
            unsigned r2 = u2 + 0x7fffu + ((u2 >> 16) & 1u);
            unsigned r3 = u3 + 0x7fffu + ((u3 >> 16) & 1u);
            uint2 pk;
            pk.x = __builtin_amdgcn_perm(r1, r0, 0x07060302u);
            pk.y = __builtin_amdgcn_perm(r3, r2, 0x07060302u);
            *(uint2*)&lds_tab[2 * j] = pk;
        }
    }
    __syncthreads();   // the ONLY barrier in this kernel

    const float rf = (float)res.r[level];
    float2* wsl = ws + (size_t)level * npts;

    const int per   = (npts + WPL - 1) / WPL;
    const int start = slice * per;
    const int end   = min(start + per, npts);

    for (int i = start + tid; i < end; i += TPB) {
        fvec4 c = *(const fvec4*)(cbuf + 4 * (size_t)i);   // 16 B coalesced

        float s0 = c.x * rf, s1 = c.y * rf, s2 = c.z * rf, s3 = c.w * rf;
        float g0 = floorf(s0), g1 = floorf(s1), g2 = floorf(s2), g3 = floorf(s3);
        float f0 = s0 - g0, f1 = s1 - g1, f2 = s2 - g2, f3 = s3 - g3;

        // primes pre-shifted <<2: (x*P)<<2 == x*(P<<2) mod 2^32
        unsigned a0 = ((unsigned)(int)g0) << 2;
        unsigned a1 = (unsigned)(int)g1 * (P1 << 2);
        unsigned a2 = (unsigned)(int)g2 * (P2 << 2);
        unsigned a3 = (unsigned)(int)g3 * (P3 << 2);
        unsigned b0 = a0 + 4u;
        unsigned b1 = a1 + (P1 << 2);
        unsigned b2 = a2 + (P2 << 2);
        unsigned b3 = a3 + (P3 << 2);

        // precombine low-pair XORs: 1 xor per gather instead of 2
        unsigned lo01[4] = { a0 ^ a1, b0 ^ a1, a0 ^ b1, b0 ^ b1 };

        float m0 = 1.0f - f0, m1 = 1.0f - f1, m2 = 1.0f - f2, m3 = 1.0f - f3;
        float w01_0 = m0 * m1, w01_1 = f0 * m1, w01_2 = m0 * f1, w01_3 = f0 * f1;
        float w23_0 = m2 * m3, w23_1 = f2 * m3, w23_2 = m2 * f3, w23_3 = f2 * f3;

        float A = 0.0f, B = 0.0f;
        #pragma unroll
        for (int hi = 0; hi < 4; ++hi) {
            unsigned hb = ((hi & 1) ? b2 : a2) ^ ((hi & 2) ? b3 : a3);
            float whi = (hi == 0) ? w23_0 : (hi == 1) ? w23_1 : (hi == 2) ? w23_2 : w23_3;
            float ax = 0.0f, ay = 0.0f;
            #pragma unroll
            for (int lo = 0; lo < 4; ++lo) {
                unsigned off = (hb ^ lo01[lo]) & MASK4;
                float wlo = (lo == 0) ? w01_0 : (lo == 1) ? w01_1 : (lo == 2) ? w01_2 : w01_3;
                unsigned pk = *(const unsigned*)((const char*)lds_tab + off);
                ax = fmaf(wlo, __uint_as_float(pk << 16), ax);
                ay = fmaf(wlo, __uint_as_float(pk & 0xffff0000u), ay);
            }
            A = fmaf(whi, ax, A);
            B = fmaf(whi, ay, B);
        }
        wsl[i] = make_float2(A, B);   // lane-contiguous f2: full sectors per instr
    }
}

// ---------------- Kernel T: ws[16][N]f2 -> out[N][32], full lines both directions.
__global__ __launch_bounds__(256, 4) void hash4d_out_kernel(
    const float* __restrict__ ws, float* __restrict__ out, int npts)
{
    __shared__ float2 lt[256][17];   // +1 pad: keeps b64/b128 at the bank minimum
    const int tid  = (int)threadIdx.x;
    const int base = (int)blockIdx.x * 256;

    if (base + 256 <= npts) {
        #pragma unroll
        for (int L = 0; L < NL; ++L) {
            // 64 lanes x 8 B contiguous = 512 B per instruction
            lt[tid][L] = ((const float2*)ws)[(size_t)L * npts + base + tid];
        }
        __syncthreads();
        const size_t ob = (size_t)base * 32;
        #pragma unroll
        for (int i = 0; i < 8; ++i) {
            int v  = i * 256 + tid;     // fvec4 index within the 256x32 tile
            int p  = v >> 3;            // local point
            int c4 = v & 7;             // 16 B chunk = level pair
            float2 e0 = lt[p][2 * c4 + 0];
            float2 e1 = lt[p][2 * c4 + 1];
            fvec4 o = { e0.x, e0.y, e1.x, e1.y };
            ((fvec4*)(out + ob))[v] = o;   // 1 KB/wave contiguous, full lines
        }
    } else {
        int p = base + tid;
        if (p < npts) {
            float* op = out + (size_t)p * 32;
            #pragma unroll
            for (int L = 0; L < NL; ++L) {
                float2 v = ((const float2*)ws)[(size_t)L * npts + p];
                op[2 * L + 0] = v.x;
                op[2 * L + 1] = v.y;
            }
        }
    }
}

// ---------------- Fallback (ws too small): direct global-gather kernel
__global__ __launch_bounds__(256, 4) void hash4d_kernel(
    const float* __restrict__ coords,
    const float* __restrict__ tstamps,
    const float* __restrict__ tables,
    float* __restrict__ out,
    int npts, ResArr res)
{
    int n = blockIdx.x * blockDim.x + threadIdx.x;
    if (n >= npts) return;

    float x = coords[3 * n + 0];
    float y = coords[3 * n + 1];
    float z = coords[3 * n + 2];
    float t = tstamps[n];
    t = fminf(fmaxf(t, 0.0f), 1.0f);

    float c0 = (x + 50.0f) / 100.0f;
    float c1 = (y + 50.0f) / 100.0f;
    float c2 = (z + 50.0f) / 100.0f;
    float c3 = t;

    const unsigned P1 = 2654435761u, P2 = 805459861u, P3 = 3674653429u;
    float acc[32];

    #pragma unroll
    for (int L = 0; L < NL; ++L) {
        float rf = (float)res.r[L];
        float s0 = c0 * rf, s1 = c1 * rf, s2 = c2 * rf, s3 = c3 * rf;
        float g0 = floorf(s0), g1 = floorf(s1), g2 = floorf(s2), g3 = floorf(s3);
        float f0 = s0 - g0, f1 = s1 - g1, f2 = s2 - g2, f3 = s3 - g3;

        unsigned a0 = (unsigned)(int)g0;
        unsigned a1 = (unsigned)(int)g1 * P1;
        unsigned a2 = (unsigned)(int)g2 * P2;
        unsigned a3 = (unsigned)(int)g3 * P3;
        unsigned b0 = a0 + 1u, b1 = a1 + P1, b2 = a2 + P2, b3 = a3 + P3;

        float w0a = 1.0f - f0, w0b = f0;
        float w1a = 1.0f - f1, w1b = f1;
        float w2a = 1.0f - f2, w2b = f2;
        float w3a = 1.0f - f3, w3b = f3;

        const float2* tab = ((const float2*)tables) + (size_t)L * (size_t)HS;
        float A = 0.0f, B = 0.0f;
        #pragma unroll
        for (int ci = 0; ci < 16; ++ci) {
            unsigned h = ((ci & 1) ? b0 : a0) ^ ((ci & 2) ? b1 : a1) ^
                         ((ci & 4) ? b2 : a2) ^ ((ci & 8) ? b3 : a3);
            float2 fv = tab[h & (HS - 1)];
            float w = ((((ci & 1) ? w0b : w0a) * ((ci & 2) ? w1b : w1a)) *
                       ((ci & 4) ? w2b : w2a)) * ((ci & 8) ? w3b : w3a);
            A += w * fv.x;
            B += w * fv.y;
        }
        acc[2 * L + 0] = A;
        acc[2 * L + 1] = B;
    }

    float* op = out + (size_t)n * 32;
    #pragma unroll
    for (int i = 0; i < 8; ++i) {
        fvec4 v = { acc[4 * i + 0], acc[4 * i + 1],
                    acc[4 * i + 2], acc[4 * i + 3] };
        *(fvec4*)(op + 4 * i) = v;
    }
}

extern "C" void kernel_launch(void* const* d_in, const int* in_sizes, int n_in,
                              void* d_out, int out_size, void* d_ws, size_t ws_size,
                              hipStream_t stream) {
    const float* coords  = (const float*)d_in[0];
    const float* tstamps = (const float*)d_in[1];
    const float* tables  = (const float*)d_in[2];
    float* out = (float*)d_out;

    // resolutions computed host-side with the same double-precision exp/log as the
    // reference (keeps int() truncation bit-identical; do NOT hardcode)
    ResArr ra;
    for (int l = 0; l < 16; ++l) {
        double f = (double)l / 15.0;
        double v = exp(log(16.0) * (1.0 - f) + log(512.0) * f);
        ra.r[l] = (int)v;
    }

    int n = in_sizes[0] / 3;
    size_t need = (size_t)n * 16 * sizeof(float2);

    // NOTE: only the ws_size guard — it is the one with measured precedent on this
    // harness (round 2 took this path). Round 4's extra out_size guard misfired and
    // silently routed to the 1.9 ms fallback; never guard on unverifiable values.
    if (ws_size >= need) {
        // c[N][4] scratch lives in the head of `out` (16 B/point = 1/8 of out).
        // Safe: stream-ordered P -> A' -> T; T fully overwrites out afterwards.
        float* cbuf = out;
        hash4d_pre_kernel<<<(n + 255) / 256, 256, 0, stream>>>(
            coords, tstamps, cbuf, n);
        hash4d_level_kernel<<<16 * WPL, TPB, 0, stream>>>(
            cbuf, tables, (float2*)d_ws, n, ra);
        hash4d_out_kernel<<<(n + 255) / 256, 256, 0, stream>>>(
            (const float*)d_ws, out, n);
    } else {
        hash4d_kernel<<<(n + 255) / 256, 256, 0, stream>>>(
            coords, tstamps, tables, out, n, ra);
    }
}

// Round 6
// 441.703 us; speedup vs baseline: 4.5837x; 1.0989x over previous
//
#include <hip/hip_runtime.h>
#include <hip/hip_fp16.h>
#include <cmath>

#define HS 32768
#define NL 16
#define WPL 16   // workgroup slices per level -> 16*16 = 256 WGs, 1/CU
#define TPB 1024

typedef float fvec4 __attribute__((ext_vector_type(4)));

struct ResArr { int r[16]; };

// ---------------- Kernel P: normalize coords ONCE (exact reference arithmetic).
// Output c[N][4] fp32 lives in the head of `out` (dead until kernel T overwrites).
__global__ __launch_bounds__(256) void hash4d_pre_kernel(
    const float* __restrict__ coords, const float* __restrict__ tstamps,
    float* __restrict__ cbuf, int npts)
{
    int p = blockIdx.x * 256 + threadIdx.x;
    if (p >= npts) return;
    float x = coords[3 * p + 0];
    float y = coords[3 * p + 1];
    float z = coords[3 * p + 2];
    float t = tstamps[p];
    t = fminf(fmaxf(t, 0.0f), 1.0f);
    // exact same ops as reference: add then true divide (bit-identical floors later)
    fvec4 c = { (x + 50.0f) / 100.0f,
                (y + 50.0f) / 100.0f,
                (z + 50.0f) / 100.0f,
                t };
    *(fvec4*)(cbuf + 4 * (size_t)p) = c;
}

// ---------------- Kernel A': one level per WG, table staged ONCE, free-running loop.
// ws[L][N] u32 (fp16x2-packed A,B) stores: 64 lanes x 4 B contiguous = 256 B per
// instruction -> sector-complete, write amp 1.0 (proven pattern, rounds 0/5).
// fp16 packing of values |v|<=~1e-4 adds <=3e-8 abs error (quantum 2^-24) vs the
// existing 4.77e-7 bf16-table error — and halves ws traffic both directions.
__global__ __launch_bounds__(TPB, 1) void hash4d_level_kernel(
    const float* __restrict__ cbuf,
    const float* __restrict__ tables,
    unsigned* __restrict__ ws,
    int npts, ResArr res)
{
    __shared__ unsigned lds_tab[HS];   // 128 KB: two bf16 feats packed per entry

    const int level = blockIdx.x & 15;
    const int slice = blockIdx.x >> 4;
    const int tid   = (int)threadIdx.x;

    const unsigned P1 = 2654435761u, P2 = 805459861u, P3 = 3674653429u;
    const unsigned MASK4 = (HS - 1u) << 2;   // hash mask pre-shifted to byte offset

    {   // stage table: fvec4 loads (2 entries), pack bf16x2 (RNE), b64 writes
        const fvec4* gt = (const fvec4*)(tables + (size_t)level * HS * 2);
        #pragma unroll 4
        for (int j = tid; j < HS / 2; j += TPB) {
            fvec4 v = gt[j];
            unsigned u0 = __float_as_uint(v.x), u1 = __float_as_uint(v.y);
            unsigned u2 = __float_as_uint(v.z), u3 = __float_as_uint(v.w);
            unsigned r0 = u0 + 0x7fffu + ((u0 >> 16) & 1u);
            unsigned r1 = u1 + 0x7fffu + ((u1 >> 16) & 1u);
            unsigned r2 = u2 + 0x7fffu + ((u2 >> 16) & 1u);
            unsigned r3 = u3 + 0x7fffu + ((u3 >> 16) & 1u);
            uint2 pk;
            pk.x = __builtin_amdgcn_perm(r1, r0, 0x07060302u);
            pk.y = __builtin_amdgcn_perm(r3, r2, 0x07060302u);
            *(uint2*)&lds_tab[2 * j] = pk;
        }
    }
    __syncthreads();   // the ONLY barrier in this kernel

    const float rf = (float)res.r[level];
    unsigned* wsl = ws + (size_t)level * npts;

    const int per   = (npts + WPL - 1) / WPL;
    const int start = slice * per;
    const int end   = min(start + per, npts);

    for (int i = start + tid; i < end; i += TPB) {
        fvec4 c = *(const fvec4*)(cbuf + 4 * (size_t)i);   // 16 B coalesced

        float s0 = c.x * rf, s1 = c.y * rf, s2 = c.z * rf, s3 = c.w * rf;
        float g0 = floorf(s0), g1 = floorf(s1), g2 = floorf(s2), g3 = floorf(s3);
        float f0 = s0 - g0, f1 = s1 - g1, f2 = s2 - g2, f3 = s3 - g3;

        // primes pre-shifted <<2: (x*P)<<2 == x*(P<<2) mod 2^32
        unsigned a0 = ((unsigned)(int)g0) << 2;
        unsigned a1 = (unsigned)(int)g1 * (P1 << 2);
        unsigned a2 = (unsigned)(int)g2 * (P2 << 2);
        unsigned a3 = (unsigned)(int)g3 * (P3 << 2);
        unsigned b0 = a0 + 4u;
        unsigned b1 = a1 + (P1 << 2);
        unsigned b2 = a2 + (P2 << 2);
        unsigned b3 = a3 + (P3 << 2);

        // precombine low-pair XORs: 1 xor per gather instead of 2
        unsigned lo01[4] = { a0 ^ a1, b0 ^ a1, a0 ^ b1, b0 ^ b1 };

        float m0 = 1.0f - f0, m1 = 1.0f - f1, m2 = 1.0f - f2, m3 = 1.0f - f3;
        float w01_0 = m0 * m1, w01_1 = f0 * m1, w01_2 = m0 * f1, w01_3 = f0 * f1;
        float w23_0 = m2 * m3, w23_1 = f2 * m3, w23_2 = m2 * f3, w23_3 = f2 * f3;

        float A = 0.0f, B = 0.0f;
        #pragma unroll
        for (int hi = 0; hi < 4; ++hi) {
            unsigned hb = ((hi & 1) ? b2 : a2) ^ ((hi & 2) ? b3 : a3);
            float whi = (hi == 0) ? w23_0 : (hi == 1) ? w23_1 : (hi == 2) ? w23_2 : w23_3;
            float ax = 0.0f, ay = 0.0f;
            #pragma unroll
            for (int lo = 0; lo < 4; ++lo) {
                unsigned off = (hb ^ lo01[lo]) & MASK4;
                float wlo = (lo == 0) ? w01_0 : (lo == 1) ? w01_1 : (lo == 2) ? w01_2 : w01_3;
                unsigned pk = *(const unsigned*)((const char*)lds_tab + off);
                ax = fmaf(wlo, __uint_as_float(pk << 16), ax);
                ay = fmaf(wlo, __uint_as_float(pk & 0xffff0000u), ay);
            }
            A = fmaf(whi, ax, A);
            B = fmaf(whi, ay, B);
        }
        __half2 h = __floats2half2_rn(A, B);   // v_cvt_pk-style pack
        wsl[i] = *(unsigned*)&h;               // 256 B/wave per instr, amp 1.0
    }
}

// ---------------- Kernel T: ws[16][N]u32 -> out[N][32]f32, full lines both dirs.
__global__ __launch_bounds__(256, 4) void hash4d_out_kernel(
    const unsigned* __restrict__ ws, float* __restrict__ out, int npts)
{
    __shared__ unsigned lt[256][17];   // 17 KB; write side stride 17 = exact 2-way (free)
    const int tid  = (int)threadIdx.x;
    const int base = (int)blockIdx.x * 256;

    if (base + 256 <= npts) {
        #pragma unroll
        for (int L = 0; L < NL; ++L) {
            // 64 lanes x 4 B contiguous = 256 B per instruction
            lt[tid][L] = ws[(size_t)L * npts + base + tid];
        }
        __syncthreads();
        const size_t ob = (size_t)base * 32;
        #pragma unroll
        for (int i = 0; i < 8; ++i) {
            int v  = i * 256 + tid;     // fvec4 index within the 256x32 tile
            int p  = v >> 3;            // local point
            int c4 = v & 7;             // 16 B chunk = level pair
            unsigned e0 = lt[p][2 * c4 + 0];
            unsigned e1 = lt[p][2 * c4 + 1];
            float2 f0 = __half22float2(*(const __half2*)&e0);
            float2 f1 = __half22float2(*(const __half2*)&e1);
            fvec4 o = { f0.x, f0.y, f1.x, f1.y };
            ((fvec4*)(out + ob))[v] = o;   // 1 KB/wave contiguous, full lines
        }
    } else {
        int p = base + tid;
        if (p < npts) {
            float* op = out + (size_t)p * 32;
            #pragma unroll
            for (int L = 0; L < NL; ++L) {
                unsigned e = ws[(size_t)L * npts + p];
                float2 f = __half22float2(*(const __half2*)&e);
                op[2 * L + 0] = f.x;
                op[2 * L + 1] = f.y;
            }
        }
    }
}

// ---------------- Fallback (ws too small): direct global-gather kernel
__global__ __launch_bounds__(256, 4) void hash4d_kernel(
    const float* __restrict__ coords,
    const float* __restrict__ tstamps,
    const float* __restrict__ tables,
    float* __restrict__ out,
    int npts, ResArr res)
{
    int n = blockIdx.x * blockDim.x + threadIdx.x;
    if (n >= npts) return;

    float x = coords[3 * n + 0];
    float y = coords[3 * n + 1];
    float z = coords[3 * n + 2];
    float t = tstamps[n];
    t = fminf(fmaxf(t, 0.0f), 1.0f);

    float c0 = (x + 50.0f) / 100.0f;
    float c1 = (y + 50.0f) / 100.0f;
    float c2 = (z + 50.0f) / 100.0f;
    float c3 = t;

    const unsigned P1 = 2654435761u, P2 = 805459861u, P3 = 3674653429u;
    float acc[32];

    #pragma unroll
    for (int L = 0; L < NL; ++L) {
        float rf = (float)res.r[L];
        float s0 = c0 * rf, s1 = c1 * rf, s2 = c2 * rf, s3 = c3 * rf;
        float g0 = floorf(s0), g1 = floorf(s1), g2 = floorf(s2), g3 = floorf(s3);
        float f0 = s0 - g0, f1 = s1 - g1, f2 = s2 - g2, f3 = s3 - g3;

        unsigned a0 = (unsigned)(int)g0;
        unsigned a1 = (unsigned)(int)g1 * P1;
        unsigned a2 = (unsigned)(int)g2 * P2;
        unsigned a3 = (unsigned)(int)g3 * P3;
        unsigned b0 = a0 + 1u, b1 = a1 + P1, b2 = a2 + P2, b3 = a3 + P3;

        float w0a = 1.0f - f0, w0b = f0;
        float w1a = 1.0f - f1, w1b = f1;
        float w2a = 1.0f - f2, w2b = f2;
        float w3a = 1.0f - f3, w3b = f3;

        const float2* tab = ((const float2*)tables) + (size_t)L * (size_t)HS;
        float A = 0.0f, B = 0.0f;
        #pragma unroll
        for (int ci = 0; ci < 16; ++ci) {
            unsigned h = ((ci & 1) ? b0 : a0) ^ ((ci & 2) ? b1 : a1) ^
                         ((ci & 4) ? b2 : a2) ^ ((ci & 8) ? b3 : a3);
            float2 fv = tab[h & (HS - 1)];
            float w = ((((ci & 1) ? w0b : w0a) * ((ci & 2) ? w1b : w1a)) *
                       ((ci & 4) ? w2b : w2a)) * ((ci & 8) ? w3b : w3a);
            A += w * fv.x;
            B += w * fv.y;
        }
        acc[2 * L + 0] = A;
        acc[2 * L + 1] = B;
    }

    float* op = out + (size_t)n * 32;
    #pragma unroll
    for (int i = 0; i < 8; ++i) {
        fvec4 v = { acc[4 * i + 0], acc[4 * i + 1],
                    acc[4 * i + 2], acc[4 * i + 3] };
        *(fvec4*)(op + 4 * i) = v;
    }
}

extern "C" void kernel_launch(void* const* d_in, const int* in_sizes, int n_in,
                              void* d_out, int out_size, void* d_ws, size_t ws_size,
                              hipStream_t stream) {
    const float* coords  = (const float*)d_in[0];
    const float* tstamps = (const float*)d_in[1];
    const float* tables  = (const float*)d_in[2];
    float* out = (float*)d_out;

    // resolutions computed host-side with the same double-precision exp/log as the
    // reference (keeps int() truncation bit-identical; do NOT hardcode)
    ResArr ra;
    for (int l = 0; l < 16; ++l) {
        double f = (double)l / 15.0;
        double v = exp(log(16.0) * (1.0 - f) + log(512.0) * f);
        ra.r[l] = (int)v;
    }

    int n = in_sizes[0] / 3;
    size_t need = (size_t)n * NL * sizeof(unsigned);   // fp16x2 ws: 128 MB at N=2M

    // Only the ws_size guard (measured precedent). Round 4's out_size guard
    // silently misrouted to the 1.9 ms fallback; never guard on unverified values.
    if (ws_size >= need) {
        // c[N][4] scratch lives in the head of `out` (16 B/point = 1/8 of out).
        // Safe: stream-ordered P -> A' -> T; T fully overwrites out afterwards.
        float* cbuf = out;
        hash4d_pre_kernel<<<(n + 255) / 256, 256, 0, stream>>>(
            coords, tstamps, cbuf, n);
        hash4d_level_kernel<<<16 * WPL, TPB, 0, stream>>>(
            cbuf, tables, (unsigned*)d_ws, n, ra);
        hash4d_out_kernel<<<(n + 255) / 256, 256, 0, stream>>>(
            (const unsigned*)d_ws, out, n);
    } else {
        hash4d_kernel<<<(n + 255) / 256, 256, 0, stream>>>(
            coords, tstamps, tables, out, n, ra);
    }
}

// Round 7
// 434.140 us; speedup vs baseline: 4.6636x; 1.0174x over previous
//
#include <hip/hip_runtime.h>
#include <hip/hip_fp16.h>
#include <cmath>

#define HS 32768
#define NL 16
#define WPL 16   // workgroup slices per level -> 16*16 = 256 WGs, 1/CU
#define TPB 1024

typedef float fvec4 __attribute__((ext_vector_type(4)));

struct ResArr { int r[16]; };

// ---------------- Kernel P: normalize coords ONCE (exact reference arithmetic).
// Output c[N][4] fp32 lives in the head of `out` (dead until kernel T overwrites).
__global__ __launch_bounds__(256) void hash4d_pre_kernel(
    const float* __restrict__ coords, const float* __restrict__ tstamps,
    float* __restrict__ cbuf, int npts)
{
    int p = blockIdx.x * 256 + threadIdx.x;
    if (p >= npts) return;
    float x = coords[3 * p + 0];
    float y = coords[3 * p + 1];
    float z = coords[3 * p + 2];
    float t = tstamps[p];
    t = fminf(fmaxf(t, 0.0f), 1.0f);
    // exact same ops as reference: add then true divide (bit-identical floors later)
    fvec4 c = { (x + 50.0f) / 100.0f,
                (y + 50.0f) / 100.0f,
                (z + 50.0f) / 100.0f,
                t };
    *(fvec4*)(cbuf + 4 * (size_t)p) = c;
}

// ---------------- Kernel A': one level per WG, table staged ONCE, free-running loop.
// Round-7 changes vs round 6 (both pure VALU cuts; ws format unchanged):
//  * tables staged as fp16x2 (MORE accurate than bf16 for |v|<=1e-4: quantum 2^-24)
//    and consumed via v_fma_mix_f32 — removes the 2-op unpack per corner.
//  * hash XOR combos pre-masked ( (x^y)&M == (x&M)^(y&M) ) — corner addr = 1 xor.
// ws[L][N] u32 (fp16x2-packed A,B): 64 lanes x 4 B = 256 B/instr, write amp 1.0.
__global__ __launch_bounds__(TPB, 1) void hash4d_level_kernel(
    const float* __restrict__ cbuf,
    const float* __restrict__ tables,
    unsigned* __restrict__ ws,
    int npts, ResArr res)
{
    __shared__ unsigned lds_tab[HS];   // 128 KB: two fp16 feats packed per entry

    const int level = blockIdx.x & 15;
    const int slice = blockIdx.x >> 4;
    const int tid   = (int)threadIdx.x;

    const unsigned P1 = 2654435761u, P2 = 805459861u, P3 = 3674653429u;
    const unsigned MASK4 = (HS - 1u) << 2;   // hash mask pre-shifted to byte offset

    {   // stage table: fvec4 loads (2 entries), pack fp16x2 (RNE), b64 writes
        const fvec4* gt = (const fvec4*)(tables + (size_t)level * HS * 2);
        #pragma unroll 4
        for (int j = tid; j < HS / 2; j += TPB) {
            fvec4 v = gt[j];
            __half2 h0 = __floats2half2_rn(v.x, v.y);
            __half2 h1 = __floats2half2_rn(v.z, v.w);
            uint2 pk;
            pk.x = *(unsigned*)&h0;
            pk.y = *(unsigned*)&h1;
            *(uint2*)&lds_tab[2 * j] = pk;
        }
    }
    __syncthreads();   // the ONLY barrier in this kernel

    const float rf = (float)res.r[level];
    unsigned* wsl = ws + (size_t)level * npts;

    const int per   = (npts + WPL - 1) / WPL;
    const int start = slice * per;
    const int end   = min(start + per, npts);

    for (int i = start + tid; i < end; i += TPB) {
        fvec4 c = *(const fvec4*)(cbuf + 4 * (size_t)i);   // 16 B coalesced

        float s0 = c.x * rf, s1 = c.y * rf, s2 = c.z * rf, s3 = c.w * rf;
        float g0 = floorf(s0), g1 = floorf(s1), g2 = floorf(s2), g3 = floorf(s3);
        float f0 = s0 - g0, f1 = s1 - g1, f2 = s2 - g2, f3 = s3 - g3;

        // primes pre-shifted <<2: (x*P)<<2 == x*(P<<2) mod 2^32
        unsigned a0 = ((unsigned)(int)g0) << 2;
        unsigned a1 = (unsigned)(int)g1 * (P1 << 2);
        unsigned a2 = (unsigned)(int)g2 * (P2 << 2);
        unsigned a3 = (unsigned)(int)g3 * (P3 << 2);
        unsigned b0 = a0 + 4u;
        unsigned b1 = a1 + (P1 << 2);
        unsigned b2 = a2 + (P2 << 2);
        unsigned b3 = a3 + (P3 << 2);

        // pre-masked XOR pairs: per-corner address is a single v_xor
        unsigned lo01m[4] = { (a0 ^ a1) & MASK4, (b0 ^ a1) & MASK4,
                              (a0 ^ b1) & MASK4, (b0 ^ b1) & MASK4 };
        unsigned hi23m[4] = { (a2 ^ a3) & MASK4, (b2 ^ a3) & MASK4,
                              (a2 ^ b3) & MASK4, (b2 ^ b3) & MASK4 };

        float m0 = 1.0f - f0, m1 = 1.0f - f1, m2 = 1.0f - f2, m3 = 1.0f - f3;
        float w01_0 = m0 * m1, w01_1 = f0 * m1, w01_2 = m0 * f1, w01_3 = f0 * f1;
        float w23_0 = m2 * m3, w23_1 = f2 * m3, w23_2 = m2 * f3, w23_3 = f2 * f3;

        float A = 0.0f, B = 0.0f;
        #pragma unroll
        for (int hi = 0; hi < 4; ++hi) {
            float whi = (hi == 0) ? w23_0 : (hi == 1) ? w23_1 : (hi == 2) ? w23_2 : w23_3;
            float ax = 0.0f, ay = 0.0f;
            #pragma unroll
            for (int lo = 0; lo < 4; ++lo) {
                unsigned off = hi23m[hi] ^ lo01m[lo];
                float wlo = (lo == 0) ? w01_0 : (lo == 1) ? w01_1 : (lo == 2) ? w01_2 : w01_3;
                unsigned pk = *(const unsigned*)((const char*)lds_tab + off);
                // fused fp16->fp32 convert + fma: no unpack ops.
                // op_sel_hi:[0,1,0] marks src1 (pk) as f16; op_sel picks the half.
                asm("v_fma_mix_f32 %0, %1, %2, %0 op_sel:[0,0,0] op_sel_hi:[0,1,0]"
                    : "+v"(ax) : "v"(wlo), "v"(pk));
                asm("v_fma_mix_f32 %0, %1, %2, %0 op_sel:[0,1,0] op_sel_hi:[0,1,0]"
                    : "+v"(ay) : "v"(wlo), "v"(pk));
            }
            A = fmaf(whi, ax, A);
            B = fmaf(whi, ay, B);
        }
        __half2 h = __floats2half2_rn(A, B);   // v_cvt_pk-style pack
        wsl[i] = *(unsigned*)&h;               // 256 B/wave per instr, amp 1.0
    }
}

// ---------------- Kernel T: ws[16][N]u32 -> out[N][32]f32, full lines both dirs.
__global__ __launch_bounds__(256, 4) void hash4d_out_kernel(
    const unsigned* __restrict__ ws, float* __restrict__ out, int npts)
{
    __shared__ unsigned lt[256][17];   // 17 KB; write side stride 17 = exact 2-way (free)
    const int tid  = (int)threadIdx.x;
    const int base = (int)blockIdx.x * 256;

    if (base + 256 <= npts) {
        #pragma unroll
        for (int L = 0; L < NL; ++L) {
            // 64 lanes x 4 B contiguous = 256 B per instruction
            lt[tid][L] = ws[(size_t)L * npts + base + tid];
        }
        __syncthreads();
        const size_t ob = (size_t)base * 32;
        #pragma unroll
        for (int i = 0; i < 8; ++i) {
            int v  = i * 256 + tid;     // fvec4 index within the 256x32 tile
            int p  = v >> 3;            // local point
            int c4 = v & 7;             // 16 B chunk = level pair
            unsigned e0 = lt[p][2 * c4 + 0];
            unsigned e1 = lt[p][2 * c4 + 1];
            float2 f0 = __half22float2(*(const __half2*)&e0);
            float2 f1 = __half22float2(*(const __half2*)&e1);
            fvec4 o = { f0.x, f0.y, f1.x, f1.y };
            ((fvec4*)(out + ob))[v] = o;   // 1 KB/wave contiguous, full lines
        }
    } else {
        int p = base + tid;
        if (p < npts) {
            float* op = out + (size_t)p * 32;
            #pragma unroll
            for (int L = 0; L < NL; ++L) {
                unsigned e = ws[(size_t)L * npts + p];
                float2 f = __half22float2(*(const __half2*)&e);
                op[2 * L + 0] = f.x;
                op[2 * L + 1] = f.y;
            }
        }
    }
}

// ---------------- Fallback (ws too small): direct global-gather kernel
__global__ __launch_bounds__(256, 4) void hash4d_kernel(
    const float* __restrict__ coords,
    const float* __restrict__ tstamps,
    const float* __restrict__ tables,
    float* __restrict__ out,
    int npts, ResArr res)
{
    int n = blockIdx.x * blockDim.x + threadIdx.x;
    if (n >= npts) return;

    float x = coords[3 * n + 0];
    float y = coords[3 * n + 1];
    float z = coords[3 * n + 2];
    float t = tstamps[n];
    t = fminf(fmaxf(t, 0.0f), 1.0f);

    float c0 = (x + 50.0f) / 100.0f;
    float c1 = (y + 50.0f) / 100.0f;
    float c2 = (z + 50.0f) / 100.0f;
    float c3 = t;

    const unsigned P1 = 2654435761u, P2 = 805459861u, P3 = 3674653429u;
    float acc[32];

    #pragma unroll
    for (int L = 0; L < NL; ++L) {
        float rf = (float)res.r[L];
        float s0 = c0 * rf, s1 = c1 * rf, s2 = c2 * rf, s3 = c3 * rf;
        float g0 = floorf(s0), g1 = floorf(s1), g2 = floorf(s2), g3 = floorf(s3);
        float f0 = s0 - g0, f1 = s1 - g1, f2 = s2 - g2, f3 = s3 - g3;

        unsigned a0 = (unsigned)(int)g0;
        unsigned a1 = (unsigned)(int)g1 * P1;
        unsigned a2 = (unsigned)(int)g2 * P2;
        unsigned a3 = (unsigned)(int)g3 * P3;
        unsigned b0 = a0 + 1u, b1 = a1 + P1, b2 = a2 + P2, b3 = a3 + P3;

        float w0a = 1.0f - f0, w0b = f0;
        float w1a = 1.0f - f1, w1b = f1;
        float w2a = 1.0f - f2, w2b = f2;
        float w3a = 1.0f - f3, w3b = f3;

        const float2* tab = ((const float2*)tables) + (size_t)L * (size_t)HS;
        float A = 0.0f, B = 0.0f;
        #pragma unroll
        for (int ci = 0; ci < 16; ++ci) {
            unsigned h = ((ci & 1) ? b0 : a0) ^ ((ci & 2) ? b1 : a1) ^
                         ((ci & 4) ? b2 : a2) ^ ((ci & 8) ? b3 : a3);
            float2 fv = tab[h & (HS - 1)];
            float w = ((((ci & 1) ? w0b : w0a) * ((ci & 2) ? w1b : w1a)) *
                       ((ci & 4) ? w2b : w2a)) * ((ci & 8) ? w3b : w3a);
            A += w * fv.x;
            B += w * fv.y;
        }
        acc[2 * L + 0] = A;
        acc[2 * L + 1] = B;
    }

    float* op = out + (size_t)n * 32;
    #pragma unroll
    for (int i = 0; i < 8; ++i) {
        fvec4 v = { acc[4 * i + 0], acc[4 * i + 1],
                    acc[4 * i + 2], acc[4 * i + 3] };
        *(fvec4*)(op + 4 * i) = v;
    }
}

extern "C" void kernel_launch(void* const* d_in, const int* in_sizes, int n_in,
                              void* d_out, int out_size, void* d_ws, size_t ws_size,
                              hipStream_t stream) {
    const float* coords  = (const float*)d_in[0];
    const float* tstamps = (const float*)d_in[1];
    const float* tables  = (const float*)d_in[2];
    float* out = (float*)d_out;

    // resolutions computed host-side with the same double-precision exp/log as the
    // reference (keeps int() truncation bit-identical; do NOT hardcode)
    ResArr ra;
    for (int l = 0; l < 16; ++l) {
        double f = (double)l / 15.0;
        double v = exp(log(16.0) * (1.0 - f) + log(512.0) * f);
        ra.r[l] = (int)v;
    }

    int n = in_sizes[0] / 3;
    size_t need = (size_t)n * NL * sizeof(unsigned);   // fp16x2 ws: 128 MB at N=2M

    // Only the ws_size guard (measured precedent). Round 4's out_size guard
    // silently misrouted to the 1.9 ms fallback; never guard on unverified values.
    if (ws_size >= need) {
        // c[N][4] scratch lives in the head of `out` (16 B/point = 1/8 of out).
        // Safe: stream-ordered P -> A' -> T; T fully overwrites out afterwards.
        float* cbuf = out;
        hash4d_pre_kernel<<<(n + 255) / 256, 256, 0, stream>>>(
            coords, tstamps, cbuf, n);
        hash4d_level_kernel<<<16 * WPL, TPB, 0, stream>>>(
            cbuf, tables, (unsigned*)d_ws, n, ra);
        hash4d_out_kernel<<<(n + 255) / 256, 256, 0, stream>>>(
            (const unsigned*)d_ws, out, n);
    } else {
        hash4d_kernel<<<(n + 255) / 256, 256, 0, stream>>>(
            coords, tstamps, tables, out, n, ra);
    }
}